// Round 1
// baseline (476.456 us; speedup 1.0000x reference)
//
#include <hip/hip_runtime.h>
#include <hip/hip_bf16.h>
#include <stdint.h>

typedef __attribute__((ext_vector_type(8))) short short8;
typedef __attribute__((ext_vector_type(4))) float floatx4;

#define BM 128
#define BN 128
#define BK 64
#define NTHREADS 256
#define GROUP_SZ 128

__device__ __forceinline__ uint32_t cvt_pk_bf16(float lo, float hi) {
    uint32_t r;
    asm("v_cvt_pk_bf16_f32 %0, %1, %2" : "=v"(r) : "v"(lo), "v"(hi));
    return r;
}

// XOR-swizzled byte offset inside a [row][128B] LDS tile (T2, 16B-slot granularity)
__device__ __forceinline__ uint32_t swz(uint32_t row, uint32_t byte_in_row) {
    return row * 128u + (byte_in_row ^ ((row & 7u) << 4));
}

__global__ __launch_bounds__(NTHREADS, 2)
void gptq_gemm_kernel(const float* __restrict__ x,
                      const int* __restrict__ qweight,
                      const float* __restrict__ scales,
                      const int* __restrict__ qzeros,
                      float* __restrict__ out,
                      int M, int K, int N) {
    __shared__ char smem[(BM * BK + BN * BK) * 2];  // 32 KiB
    char* Ald = smem;                 // [BM][BK] bf16, swizzled (k contiguous)
    char* Bld = smem + BM * BK * 2;   // [BN][BK] bf16, swizzled (k contiguous per n)

    const int nbm = M / BM, nbn = N / BN;
    const int nwg = nbm * nbn;
    // bijective XCD-aware swizzle (m204 formula)
    int bid = blockIdx.x;
    int q = nwg >> 3, r = nwg & 7;
    int xcd = bid & 7, lin = bid >> 3;
    int sid = (xcd < r ? xcd * (q + 1) : r * (q + 1) + (xcd - r) * q) + lin;
    int bm = sid / nbn, bn = sid % nbn;
    const int m0 = bm * BM, n0 = bn * BN;

    const int t = threadIdx.x;
    const int lane = t & 63, wave = t >> 6;

    // A staging: thread covers rows (i*16 + tm), k-quad tk4 (4 floats = 16B)
    const int tm = t >> 4;          // 0..15
    const int tk4 = t & 15;         // 0..15 -> k offset tk4*4
    // B staging: thread covers column sn, qweight word-half kwh (4 words of 8 k each)
    const int sn = t & 127;         // 0..127
    const int kwh = t >> 7;         // 0..1

    const int gn = n0 + sn;
    const int NT = K / BK;

    // per-tile staging registers
    float4 av[8];
    uint32_t qw[4];
    float sc, nz;

    auto load_tile = [&](int ts) {
        const int k0 = ts * BK;
        const float* xb = x + (size_t)(m0 + tm) * K + k0 + tk4 * 4;
        #pragma unroll
        for (int i = 0; i < 8; ++i)
            av[i] = *reinterpret_cast<const float4*>(xb + (size_t)i * 16 * K);
        const int g = k0 >> 7;  // GROUP_SZ = 128
        sc = scales[(size_t)g * N + gn];
        const uint32_t zw = (uint32_t)qzeros[(size_t)g * (N >> 3) + (gn >> 3)];
        const float z = (float)((zw >> ((gn & 7) * 4)) & 15u) + 1.0f;
        nz = -z * sc;  // W = sc*q + nz
        const int* qb = qweight + (size_t)((k0 >> 3) + kwh * 4) * N + gn;
        #pragma unroll
        for (int j = 0; j < 4; ++j)
            qw[j] = (uint32_t)qb[(size_t)j * N];
    };

    auto write_tile = [&]() {
        // A: fp32 -> bf16, 8 rows x 4 elems each
        #pragma unroll
        for (int i = 0; i < 8; ++i) {
            uint2 p;
            p.x = cvt_pk_bf16(av[i].x, av[i].y);
            p.y = cvt_pk_bf16(av[i].z, av[i].w);
            *reinterpret_cast<uint2*>(Ald + swz((uint32_t)(i * 16 + tm), (uint32_t)(tk4 * 8))) = p;
        }
        // B: unpack 4 words x 8 nibbles, dequant, 8 bf16 = 16B per word
        #pragma unroll
        for (int j = 0; j < 4; ++j) {
            const uint32_t w = qw[j];
            float f[8];
            #pragma unroll
            for (int e = 0; e < 8; ++e)
                f[e] = fmaf((float)((w >> (4 * e)) & 15u), sc, nz);
            uint4 p;
            p.x = cvt_pk_bf16(f[0], f[1]);
            p.y = cvt_pk_bf16(f[2], f[3]);
            p.z = cvt_pk_bf16(f[4], f[5]);
            p.w = cvt_pk_bf16(f[6], f[7]);
            *reinterpret_cast<uint4*>(Bld + swz((uint32_t)sn, (uint32_t)((kwh * 4 + j) * 16))) = p;
        }
    };

    // accumulators: wave (wm,wn) owns 64x64 = 4x4 fragments of 16x16
    floatx4 acc[4][4];
    const floatx4 fzero = {0.f, 0.f, 0.f, 0.f};
    #pragma unroll
    for (int i = 0; i < 4; ++i)
        #pragma unroll
        for (int j = 0; j < 4; ++j)
            acc[i][j] = fzero;

    const int wm = (wave >> 1) * 64, wn = (wave & 1) * 64;
    const int fr = lane & 15;                 // fragment row (A) / col (B)
    const int fkb = ((lane >> 4) * 8) * 2;    // byte offset of this lane's 8-k chunk

    auto compute = [&]() {
        #pragma unroll
        for (int kk = 0; kk < 2; ++kk) {
            short8 af[4], bf[4];
            #pragma unroll
            for (int i = 0; i < 4; ++i)
                af[i] = *reinterpret_cast<const short8*>(
                    Ald + swz((uint32_t)(wm + i * 16 + fr), (uint32_t)(kk * 64 + fkb)));
            #pragma unroll
            for (int i = 0; i < 4; ++i)
                bf[i] = *reinterpret_cast<const short8*>(
                    Bld + swz((uint32_t)(wn + i * 16 + fr), (uint32_t)(kk * 64 + fkb)));
            #pragma unroll
            for (int i = 0; i < 4; ++i)
                #pragma unroll
                for (int j = 0; j < 4; ++j)
                    acc[i][j] = __builtin_amdgcn_mfma_f32_16x16x32_bf16(af[i], bf[j], acc[i][j], 0, 0, 0);
        }
    };

    // ---- main loop: single LDS buffer + register prefetch (T14) ----
    load_tile(0);
    write_tile();
    __syncthreads();
    for (int ts = 0; ts < NT; ++ts) {
        if (ts + 1 < NT) load_tile(ts + 1);   // issue-early: overlaps MFMA below
        compute();
        __syncthreads();                      // all waves done reading LDS
        if (ts + 1 < NT) write_tile();        // write-late (waits loads via vmcnt)
        __syncthreads();
    }

    // ---- epilogue: C/D layout col=lane&15, row=(lane>>4)*4+reg ----
    const int fq = lane >> 4;
    float* op = out + (size_t)(m0 + wm) * N + n0 + wn;
    #pragma unroll
    for (int i = 0; i < 4; ++i)
        #pragma unroll
        for (int j = 0; j < 4; ++j)
            #pragma unroll
            for (int rr = 0; rr < 4; ++rr)
                op[(size_t)(i * 16 + fq * 4 + rr) * N + j * 16 + fr] = acc[i][j][rr];
}

extern "C" void kernel_launch(void* const* d_in, const int* in_sizes, int n_in,
                              void* d_out, int out_size, void* d_ws, size_t ws_size,
                              hipStream_t stream) {
    const float* x       = (const float*)d_in[0];
    const int*   qweight = (const int*)d_in[1];
    const float* scales  = (const float*)d_in[2];
    const int*   qzeros  = (const int*)d_in[3];
    // d_in[4] (g_idx) is the standard k//128 grouping; computed directly in-kernel.

    const int K = in_sizes[4];
    const int M = in_sizes[0] / K;
    const int G = K / GROUP_SZ;
    const int N = in_sizes[2] / G;
    float* out = (float*)d_out;

    const int nwg = (M / BM) * (N / BN);
    hipLaunchKernelGGL(gptq_gemm_kernel, dim3(nwg), dim3(NTHREADS), 0, stream,
                       x, qweight, scales, qzeros, out, M, K, N);
}